// Round 1
// 857.541 us; speedup vs baseline: 1.2585x; 1.2585x over previous
//
#include <hip/hip_runtime.h>

#define B_ROWS 8192
#define DIM_   4096
#define HID_   256
#define NH_    16
#define SEQ_   2048

typedef __attribute__((ext_vector_type(8))) short short8;
typedef __attribute__((ext_vector_type(4))) float float4v;
typedef unsigned short ushort_t;

typedef const void __attribute__((address_space(1)))* as1_cvp;
typedef void __attribute__((address_space(3)))* as3_vp;

__device__ __forceinline__ void gload_lds16(const void* g, void* l) {
  __builtin_amdgcn_global_load_lds((as1_cvp)g, (as3_vp)l, 16, 0, 0);
}

// RNE float -> bf16 (finite inputs only)
__device__ __forceinline__ ushort_t f2bf(float f) {
  union { float f; unsigned u; } a;
  a.f = f;
  unsigned r = a.u + 0x7FFFu + ((a.u >> 16) & 1u);
  return (ushort_t)(r >> 16);
}
__device__ __forceinline__ float bf2f(ushort_t v) {
  union { unsigned u; float f; } a;
  a.u = ((unsigned)v) << 16;
  return a.f;
}

// ---------------- merged prep kernel (unchanged) ---------------------------
__global__ __launch_bounds__(256)
void uber_prep(const float* __restrict__ x, ushort_t* __restrict__ xbf,
               const float* __restrict__ caches, const float* __restrict__ w_mix,
               const float* __restrict__ b_mix, const float* __restrict__ decay,
               const int* __restrict__ index, ushort_t* __restrict__ E,
               const float* __restrict__ W_proj, ushort_t* __restrict__ Bt) {
  __shared__ float tile[64][65];
  const int bid = blockIdx.x;
  const int tid = threadIdx.x;
  if (bid < 8192) {
    const long base = (long)bid * 4096 + tid * 4;
    #pragma unroll
    for (int j = 0; j < 4; ++j) {
      const long i = base + j * 1024;
      const float4v v = *(const float4v*)(x + i);
      ushort4 o;
      o.x = f2bf(v.x); o.y = f2bf(v.y); o.z = f2bf(v.z); o.w = f2bf(v.w);
      *(ushort4*)(xbf + i) = o;
    }
  } else if (bid < 16384) {
    const int b2 = bid - 8192;
    const int h = b2 >> 9;
    const int idx = *index;
    const float w = w_mix[h * SEQ_ + idx];
    const float bc = b_mix[h * SEQ_ + idx];
    float d = fminf(fmaxf(decay[h], 0.9f), 1.0f);
    d = powf(d, 0.25f);
    const float cc = (h < NH_ / 2) ? (w * d) : d;
    const long base = (long)b2 * 4096 + tid * 4;
    #pragma unroll
    for (int j = 0; j < 4; ++j) {
      const long i = base + j * 1024;
      const long rem = i & ((1L << 21) - 1);
      const int bb = (int)(rem >> 8);
      const int kk = (int)(rem & 255);
      const float4v v = *(const float4v*)(caches + i);
      ushort4 o;
      o.x = f2bf(cc * v.x + bc); o.y = f2bf(cc * v.y + bc);
      o.z = f2bf(cc * v.z + bc); o.w = f2bf(cc * v.w + bc);
      *(ushort4*)(E + (long)bb * DIM_ + h * HID_ + kk) = o;
    }
  } else {
    const int b2 = bid - 16384;
    const int h = b2 >> 8;
    const int t = b2 & 255;
    const int M0 = (t & 63) * 64;
    const int N0 = (t >> 6) * 64;
    const float* src = W_proj + (long)h * DIM_ * HID_;
    #pragma unroll
    for (int j = 0; j < 4; ++j) {
      const int row = (tid >> 4) + j * 16;
      const int c = (tid & 15) * 4;
      const float4v v = *(const float4v*)(src + (long)(M0 + row) * HID_ + N0 + c);
      tile[row][c] = v.x; tile[row][c + 1] = v.y;
      tile[row][c + 2] = v.z; tile[row][c + 3] = v.w;
    }
    __syncthreads();
    ushort_t* dst = Bt + (long)h * HID_ * DIM_;
    #pragma unroll
    for (int j = 0; j < 4; ++j) {
      const int orow = (tid >> 4) + j * 16;
      const int oc = (tid & 15) * 4;
      ushort4 o;
      o.x = f2bf(tile[oc][orow]);     o.y = f2bf(tile[oc + 1][orow]);
      o.z = f2bf(tile[oc + 2][orow]); o.w = f2bf(tile[oc + 3][orow]);
      *(ushort4*)(dst + (long)(N0 + orow) * DIM_ + M0 + oc) = o;
    }
  }
}

// ---------- transpose-convert W_out (unchanged) ----------------------------
__global__ __launch_bounds__(256)
void tr_wout(const float* __restrict__ in, ushort_t* __restrict__ out) {
  __shared__ float tile[64][65];
  const int tid = threadIdx.x;
  const int t = blockIdx.x;
  const int M0 = (t & 63) * 64;
  const int N0 = (t >> 6) * 64;
  #pragma unroll
  for (int j = 0; j < 4; ++j) {
    const int row = (tid >> 4) + j * 16;
    const int c = (tid & 15) * 4;
    const float4v v = *(const float4v*)(in + (long)(M0 + row) * DIM_ + N0 + c);
    tile[row][c] = v.x; tile[row][c + 1] = v.y;
    tile[row][c + 2] = v.z; tile[row][c + 3] = v.w;
  }
  __syncthreads();
  #pragma unroll
  for (int j = 0; j < 4; ++j) {
    const int orow = (tid >> 4) + j * 16;
    const int oc = (tid & 15) * 4;
    ushort4 o;
    o.x = f2bf(tile[oc][orow]);     o.y = f2bf(tile[oc + 1][orow]);
    o.z = f2bf(tile[oc + 2][orow]); o.w = f2bf(tile[oc + 3][orow]);
    *(ushort4*)(out + (long)(N0 + orow) * DIM_ + M0 + oc) = o;
  }
}

// ============ 256x256 8-phase bf16 GEMM (m201-class structure) =============
// C = A(MxK) * Bt(NxK)^T. 512 thr = 8 waves (2Mx4N), per-wave C = 128x64.
// LDS 128 KiB: 2 buffers x {A_q0,A_q1,B_q0,B_q1} 16 KiB regions.
// Region = the 128 rows consumed by one quadrant-phase across all waves,
// so each region dies at a known phase and its re-stage is issued only
// after the barrier following its last ds_read (race-free by construction).
// vmcnt(6) at phases 4/8 keeps 3 region-stages (6 loads) in flight across
// barriers; never drains to 0 in the main loop.
template <int EPI>
__launch_bounds__(512, 2)
__global__ void gemm256(const ushort_t* __restrict__ A, const ushort_t* __restrict__ Bt,
                        const float* __restrict__ b_proj, const ushort_t* __restrict__ E,
                        const float* __restrict__ w_mix, const int* __restrict__ index,
                        const float* __restrict__ b_out,
                        ushort_t* __restrict__ hid_out, float* __restrict__ f_out) {
  __shared__ __attribute__((aligned(16))) ushort_t lds[65536];  // 128 KiB
  const int tid = threadIdx.x;
  const int lane = tid & 63;
  const int wave = tid >> 6;      // 0..7
  const int wm = wave >> 2;       // 0..1  (M)
  const int wn = wave & 3;        // 0..3  (N)
  const int r16 = lane & 15;
  const int quad = lane >> 4;
  const int r7 = r16 & 7;
  const int wm64 = wm * 64;
  const int wn32 = wn * 32;
  const int m0 = blockIdx.y * 256;
  const int n0 = blockIdx.x * 256;

  const ushort_t* Abase = A + (long)m0 * DIM_;
  const ushort_t* Bbase = Bt + (long)n0 * DIM_;

  // per-thread staging source offsets (granule XOR pre-swizzle; LDS dest linear)
  const int lrow = tid >> 3;                             // 0..63
  const int g8 = (((tid & 7) ^ (lrow & 7)) * 8);
  const long oA = (long)lrow * DIM_ + g8;                // A region, granule 0
  const long oB = (long)((lrow >> 5) * 64 + (lrow & 31)) * DIM_ + g8;  // B region
  // granule 1 (c = tid+512) is exactly +128 rows for both A and B regions.

  float4v acc[8][4];
  #pragma unroll
  for (int i = 0; i < 8; ++i)
    #pragma unroll
    for (int j = 0; j < 4; ++j)
      acc[i][j] = (float4v){0.f, 0.f, 0.f, 0.f};

  short8 a[4][2];      // A frags of current mh-quadrant
  short8 b[2][2][2];   // B frags of both nh-quadrants (held across the K-tile)

#define STAGE_A(buf, q, kt_) do {                                             \
    const ushort_t* ga = Abase + (long)(kt_) * 64 + (q) * (64L * DIM_) + oA;  \
    ushort_t* lb = lds + (buf) * 32768 + (q) * 8192 + tid * 8;                \
    gload_lds16(ga, lb);                                                      \
    gload_lds16(ga + 128L * DIM_, lb + 4096);                                 \
  } while (0)

#define STAGE_B(buf, q, kt_) do {                                             \
    const ushort_t* gb = Bbase + (long)(kt_) * 64 + (q) * (32L * DIM_) + oB;  \
    ushort_t* lb = lds + (buf) * 32768 + 16384 + (q) * 8192 + tid * 8;        \
    gload_lds16(gb, lb);                                                      \
    gload_lds16(gb + 128L * DIM_, lb + 4096);                                 \
  } while (0)

#define READ_A(buf, mh) do {                                                  \
    const ushort_t* Ar = lds + (buf) * 32768 + (mh) * 8192;                   \
    _Pragma("unroll")                                                         \
    for (int mi = 0; mi < 4; ++mi)                                            \
      _Pragma("unroll")                                                       \
      for (int ks = 0; ks < 2; ++ks)                                          \
        a[mi][ks] = *(const short8*)(Ar + (wm64 + mi * 16 + r16) * 64 +       \
                                     ((ks * 4 + quad) ^ r7) * 8);             \
  } while (0)

#define READ_B(buf, nh) do {                                                  \
    const ushort_t* Br = lds + (buf) * 32768 + 16384 + (nh) * 8192;           \
    _Pragma("unroll")                                                         \
    for (int nj = 0; nj < 2; ++nj)                                            \
      _Pragma("unroll")                                                       \
      for (int ks = 0; ks < 2; ++ks)                                          \
        b[nh][nj][ks] = *(const short8*)(Br + (wn32 + nj * 16 + r16) * 64 +   \
                                         ((ks * 4 + quad) ^ r7) * 8);         \
  } while (0)

#define MFMA_Q(mh, nh) do {                                                   \
    _Pragma("unroll")                                                         \
    for (int mi = 0; mi < 4; ++mi)                                            \
      _Pragma("unroll")                                                       \
      for (int nj = 0; nj < 2; ++nj)                                          \
        _Pragma("unroll")                                                     \
        for (int ks = 0; ks < 2; ++ks)                                        \
          acc[(mh) * 4 + mi][(nh) * 2 + nj] =                                 \
              __builtin_amdgcn_mfma_f32_16x16x32_bf16(                        \
                  a[mi][ks], b[nh][nj][ks], acc[(mh) * 4 + mi][(nh) * 2 + nj],\
                  0, 0, 0);                                                   \
  } while (0)

#define VMCNT6() asm volatile("s_waitcnt vmcnt(6)" ::: "memory")
#define PH_MID() do { __builtin_amdgcn_s_barrier();                           \
    asm volatile("s_waitcnt lgkmcnt(0)" ::: "memory");                        \
    __builtin_amdgcn_s_setprio(1); } while (0)
#define PH_END() do { __builtin_amdgcn_s_setprio(0);                          \
    __builtin_amdgcn_s_barrier(); } while (0)

  // Prologue: tile0 complete + first 3 regions of tile1 (7 regions, 14 loads).
  STAGE_A(0, 0, 0); STAGE_B(0, 0, 0); STAGE_B(0, 1, 0); STAGE_A(0, 1, 0);
  STAGE_A(1, 0, 1); STAGE_B(1, 0, 1); STAGE_B(1, 1, 1);
  VMCNT6();                       // tile0 landed; tile1's 3 regions in flight
  __builtin_amdgcn_s_barrier();

  for (int it = 0; it < 32; ++it) {
    const int T = 2 * it;
    const int kt2 = (it < 31) ? T + 2 : 63;  // clamped garbage lands in dead
    const int kt3 = (it < 31) ? T + 3 : 63;  // regions on the last iteration
    // ph1: buf0.A_q0+B_q0 read; stage (T+1).A_q1 (buf1.A_q1 died prev ph7)
    READ_A(0, 0); READ_B(0, 0);
    STAGE_A(1, 1, T + 1);
    PH_MID(); MFMA_Q(0, 0); PH_END();
    // ph2: buf0.B_q1 read; stage (T+2).A_q0 (buf0.A_q0 died ph1)
    READ_B(0, 1);
    STAGE_A(0, 0, kt2);
    PH_MID(); MFMA_Q(0, 1); PH_END();
    // ph3: buf0.A_q1 read; stage (T+2).B_q0 (buf0.B_q0 died ph1)
    READ_A(0, 1);
    STAGE_B(0, 0, kt2);
    PH_MID(); MFMA_Q(1, 0); PH_END();
    // ph4: stage (T+2).B_q1 (died ph2); counted wait -> tile T+1 landed
    STAGE_B(0, 1, kt2);
    VMCNT6();
    PH_MID(); MFMA_Q(1, 1); PH_END();
    // ph5: buf1 tile T+1; stage (T+2).A_q1 (buf0.A_q1 died ph3)
    READ_A(1, 0); READ_B(1, 0);
    STAGE_A(0, 1, kt2);
    PH_MID(); MFMA_Q(0, 0); PH_END();
    // ph6: stage (T+3).A_q0 (buf1.A_q0 died ph5)
    READ_B(1, 1);
    STAGE_A(1, 0, kt3);
    PH_MID(); MFMA_Q(0, 1); PH_END();
    // ph7: stage (T+3).B_q0 (buf1.B_q0 died ph5)
    READ_A(1, 1);
    STAGE_B(1, 0, kt3);
    PH_MID(); MFMA_Q(1, 0); PH_END();
    // ph8: stage (T+3).B_q1 (died ph6); counted wait -> tile T+2 landed
    STAGE_B(1, 1, kt3);
    VMCNT6();
    PH_MID(); MFMA_Q(1, 1); PH_END();
  }

  // drain in-flight (garbage) stages before reusing LDS for the epilogue
  asm volatile("s_waitcnt vmcnt(0)" ::: "memory");
  __builtin_amdgcn_s_barrier();

  // Epilogue. C/D frag layout: col = lane&15, row = (lane>>4)*4 + reg.
  // acc[mig][nig] covers rows wm*128 + mig*16, cols wn*64 + nig*16.
  if (EPI == 0) {
    // hid = w[h]*(acc + b_proj) + E  -> bf16; full 256x256 bf16 tile in LDS
    const int idx0 = *index;
    #pragma unroll
    for (int nig = 0; nig < 4; ++nig) {
      const int col = wn * 64 + nig * 16 + r16;
      const int gcol = n0 + col;
      const float wc = w_mix[(gcol >> 8) * SEQ_ + idx0];
      const float bp = b_proj[gcol];
      #pragma unroll
      for (int mig = 0; mig < 8; ++mig)
        #pragma unroll
        for (int r = 0; r < 4; ++r) {
          const int lr = wm * 128 + mig * 16 + quad * 4 + r;
          lds[lr * 256 + col] = f2bf(wc * (acc[mig][nig][r] + bp));
        }
    }
    __syncthreads();
    #pragma unroll
    for (int j = 0; j < 16; ++j) {
      const int idx = tid + j * 512;
      const int row = idx >> 5;
      const int seg = idx & 31;
      const short8 c8 = *(const short8*)(lds + row * 256 + seg * 8);
      const short8 e8 = *(const short8*)(E + (long)(m0 + row) * DIM_ + n0 + seg * 8);
      short8 o;
      #pragma unroll
      for (int k = 0; k < 8; ++k)
        o[k] = (short)f2bf(bf2f((ushort_t)c8[k]) + bf2f((ushort_t)e8[k]));
      *(short8*)(hid_out + (long)(m0 + row) * DIM_ + n0 + seg * 8) = o;
    }
  } else {
    // out = acc + b_out -> fp32, two 128-row halves (128x256 f32 = 128 KiB)
    float* Cf = (float*)lds;
    #pragma unroll
    for (int half = 0; half < 2; ++half) {
      __syncthreads();
      if (wm == half) {
        #pragma unroll
        for (int nig = 0; nig < 4; ++nig) {
          const int col = wn * 64 + nig * 16 + r16;
          #pragma unroll
          for (int mig = 0; mig < 8; ++mig)
            #pragma unroll
            for (int r = 0; r < 4; ++r)
              Cf[(mig * 16 + quad * 4 + r) * 256 + col] = acc[mig][nig][r];
        }
      }
      __syncthreads();
      #pragma unroll
      for (int j = 0; j < 16; ++j) {
        const int idx = tid + j * 512;
        const int row = idx >> 6;
        const int seg = idx & 63;
        float4v v = *(const float4v*)(Cf + row * 256 + seg * 4);
        const float4v bo = *(const float4v*)(b_out + n0 + seg * 4);
        v.x += bo.x; v.y += bo.y; v.z += bo.z; v.w += bo.w;
        *(float4v*)(f_out + (long)(m0 + half * 128 + row) * DIM_ + n0 + seg * 4) = v;
      }
    }
  }
#undef STAGE_A
#undef STAGE_B
#undef READ_A
#undef READ_B
#undef MFMA_Q
#undef VMCNT6
#undef PH_MID
#undef PH_END
}

extern "C" void kernel_launch(void* const* d_in, const int* in_sizes, int n_in,
                              void* d_out, int out_size, void* d_ws, size_t ws_size,
                              hipStream_t stream) {
  const float* x       = (const float*)d_in[0];
  const int*   index   = (const int*)d_in[1];
  const float* W_proj  = (const float*)d_in[2];
  const float* b_proj  = (const float*)d_in[3];
  const float* W_out   = (const float*)d_in[4];
  const float* b_out   = (const float*)d_in[5];
  const float* w_mix   = (const float*)d_in[6];
  const float* b_mix   = (const float*)d_in[7];
  const float* decay   = (const float*)d_in[8];
  const float* caches  = (const float*)d_in[9];
  float* out = (float*)d_out;

  char* ws = (char*)d_ws;
  // layout: xbf 64MB | Bt 32MB (Wproj^T, then Wout^T) | hid 64MB | E 64MB
  ushort_t* xbf  = (ushort_t*)(ws);
  ushort_t* Bt   = (ushort_t*)(ws + 67108864L);
  ushort_t* hid  = (ushort_t*)(ws + 100663296L);
  ushort_t* Ebuf = (ushort_t*)(ws + 167772160L);

  hipLaunchKernelGGL(uber_prep, dim3(20480), dim3(256), 0, stream,
                     x, xbf, caches, w_mix, b_mix, decay, index, Ebuf, W_proj, Bt);
  hipLaunchKernelGGL((gemm256<0>), dim3(DIM_ / 256, B_ROWS / 256), dim3(512), 0, stream,
                     xbf, Bt, b_proj, Ebuf, w_mix, index, b_out, hid, out);
  hipLaunchKernelGGL(tr_wout, dim3(4096), dim3(256), 0, stream, W_out, Bt);
  hipLaunchKernelGGL((gemm256<1>), dim3(DIM_ / 256, B_ROWS / 256), dim3(512), 0, stream,
                     hid, Bt, b_proj, Ebuf, w_mix, index, b_out, hid, out);
}